// Round 3
// baseline (626.286 us; speedup 1.0000x reference)
//
#include <hip/hip_runtime.h>
#include <hip/hip_bf16.h>
#include <stdint.h>

#define D_MODEL 1024
#define NH 16
#define SEQ 512
#define DK 64
#define BATCH 16
#define M_TOT (BATCH*SEQ)   // 8192

typedef unsigned short u16;
typedef unsigned int u32;
typedef __attribute__((ext_vector_type(8))) __bf16 bf16x8;
typedef __attribute__((ext_vector_type(8))) u16 ushort8;
typedef __attribute__((ext_vector_type(4))) u16 ushort4v;
typedef __attribute__((ext_vector_type(4))) float f32x4;

static __device__ __forceinline__ u16 f2bf(float f) {
    union { float f; u32 i; } c; c.f = f;
    u32 u = c.i;
    return (u16)((u + 0x7FFFu + ((u >> 16) & 1u)) >> 16);
}

// ---------------- f32 -> bf16 convert (x) ----------------
__global__ __launch_bounds__(256) void convert_f32_bf16(const float* __restrict__ in,
                                                        u16* __restrict__ out) {
    const int i = (blockIdx.x * 256 + threadIdx.x) * 4;
    float4 v = *(const float4*)&in[i];
    ushort4v o;
    o[0] = f2bf(v.x); o[1] = f2bf(v.y); o[2] = f2bf(v.z); o[3] = f2bf(v.w);
    *(ushort4v*)&out[i] = o;
}

// ------------- weight transpose + convert: Wt[n][k] = bf16(W[k][n]) -------------
__global__ __launch_bounds__(256) void transpose_w(const float* __restrict__ W,
                                                   u16* __restrict__ Wt) {
    __shared__ u16 tile[64][65];
    const int n0 = blockIdx.x * 64, k0 = blockIdx.y * 64;
    const int t = threadIdx.x;
    #pragma unroll
    for (int p = 0; p < 16; ++p) {
        int idx = p * 256 + t;
        int r = idx >> 6, c = idx & 63;
        tile[r][c] = f2bf(W[(size_t)(k0 + r) * D_MODEL + (n0 + c)]);
    }
    __syncthreads();
    #pragma unroll
    for (int p = 0; p < 16; ++p) {
        int idx = p * 256 + t;
        int r = idx >> 6, c = idx & 63;
        Wt[(size_t)(n0 + r) * D_MODEL + (k0 + c)] = tile[c][r];
    }
}

// ------------- C[m,n] = A[m,:]·Bt[n,:] + bias[n]  (BT-form bf16 GEMM) -------------
// mode 0: scatter bf16 to [B,H,S,DK] (qkv);  mode 1: plain f32 [M, D_MODEL]
__global__ __launch_bounds__(256) void gemm_bt(const u16* __restrict__ A,
                                               const u16* __restrict__ Bt,
                                               const float* __restrict__ bias,
                                               void* __restrict__ outv,
                                               int mode) {
    __shared__ __attribute__((aligned(16))) u16 Asm[128 * 64];
    __shared__ __attribute__((aligned(16))) u16 Bsm[128 * 64];
    const int t = threadIdx.x;
    const int m0 = blockIdx.y * 128, n0 = blockIdx.x * 128;
    const int lane = t & 63, w = t >> 6;
    const int lm = lane & 15, quad = lane >> 4;
    const int wm = w >> 1, wn = w & 1;

    f32x4 acc[4][4];
    #pragma unroll
    for (int i = 0; i < 4; ++i)
        #pragma unroll
        for (int j = 0; j < 4; ++j) acc[i][j] = (f32x4){0.f, 0.f, 0.f, 0.f};

    for (int kt = 0; kt < D_MODEL / 64; ++kt) {
        const int k0 = kt * 64;
        uint4 areg[4], breg[4];
        #pragma unroll
        for (int i = 0; i < 4; ++i) {
            int chunk = i * 256 + t;
            int row = chunk >> 3, c16 = chunk & 7;
            areg[i] = *(const uint4*)&A[(size_t)(m0 + row) * D_MODEL + k0 + c16 * 8];
            breg[i] = *(const uint4*)&Bt[(size_t)(n0 + row) * D_MODEL + k0 + c16 * 8];
        }
        __syncthreads();   // prior-iteration LDS readers done before overwrite
        #pragma unroll
        for (int i = 0; i < 4; ++i) {
            int chunk = i * 256 + t;
            *(uint4*)&Asm[chunk * 8] = areg[i];
            *(uint4*)&Bsm[chunk * 8] = breg[i];
        }
        __syncthreads();
        #pragma unroll
        for (int ks = 0; ks < 64; ks += 32) {
            bf16x8 af[4], bfv[4];
            #pragma unroll
            for (int im = 0; im < 4; ++im)
                af[im] = *(const bf16x8*)&Asm[(wm * 64 + im * 16 + lm) * 64 + ks + quad * 8];
            #pragma unroll
            for (int in = 0; in < 4; ++in)
                bfv[in] = *(const bf16x8*)&Bsm[(wn * 64 + in * 16 + lm) * 64 + ks + quad * 8];
            #pragma unroll
            for (int im = 0; im < 4; ++im)
                #pragma unroll
                for (int in = 0; in < 4; ++in)
                    acc[im][in] = __builtin_amdgcn_mfma_f32_16x16x32_bf16(
                        af[im], bfv[in], acc[im][in], 0, 0, 0);
        }
    }
    #pragma unroll
    for (int in = 0; in < 4; ++in) {
        const int n = n0 + wn * 64 + in * 16 + lm;
        const float bv = bias[n];
        #pragma unroll
        for (int im = 0; im < 4; ++im) {
            #pragma unroll
            for (int r = 0; r < 4; ++r) {
                const int m = m0 + wm * 64 + im * 16 + quad * 4 + r;
                const float val = acc[im][in][r] + bv;
                if (mode == 0) {
                    int b = m >> 9, s = m & 511, h = n >> 6, d = n & 63;
                    ((u16*)outv)[((size_t)(b * NH + h) * SEQ + s) * DK + d] = f2bf(val);
                } else {
                    ((float*)outv)[(size_t)m * D_MODEL + n] = val;
                }
            }
        }
    }
}

// ---------------- fused attention: one block per (b, h, 16-row q tile) ----------------
__global__ __launch_bounds__(256) void attn_kernel(const u16* __restrict__ qws,
                                                   const u16* __restrict__ kws,
                                                   const u16* __restrict__ vws,
                                                   const float* __restrict__ rel,
                                                   u16* __restrict__ attn_out) {
    __shared__ __attribute__((aligned(16))) float Sst[16][516];   // 33 KB fp32 score strip
    __shared__ __attribute__((aligned(16))) u16 qt[16][80];
    __shared__ __attribute__((aligned(16))) u16 kvt[64][80];
    __shared__ __attribute__((aligned(16))) float biasb[528];
    __shared__ float linv[16];

    const int t = threadIdx.x;
    const int lane = t & 63, w = t >> 6;
    const int lm = lane & 15, quad = lane >> 4;
    const int q0 = blockIdx.x * 16;
    const int h = blockIdx.y, b = blockIdx.z;
    const size_t bh = (size_t)(b * NH + h);
    const u16* qbase = qws + bh * SEQ * DK;
    const u16* kbase = kws + bh * SEQ * DK;
    const u16* vbase = vws + bh * SEQ * DK;

    if (t < 128) {
        int row = t >> 3, c16 = t & 7;
        *(uint4*)&qt[row][c16 * 8] = *(const uint4*)&qbase[(q0 + row) * DK + c16 * 8];
    }
    for (int u = t; u < 527; u += 256)
        biasb[u] = rel[(q0 + u) * NH + h];

    const float scale = 0.125f;  // 1/sqrt(64)

    // ---- QK^T phase: Sst[i][j] = q·k * scale + bias ----
    for (int jt = 0; jt < 8; ++jt) {
        const int j0 = jt * 64;
        #pragma unroll
        for (int i = 0; i < 2; ++i) {
            int chunk = i * 256 + t;
            int row = chunk >> 3, c16 = chunk & 7;
            *(uint4*)&kvt[row][c16 * 8] = *(const uint4*)&kbase[(j0 + row) * DK + c16 * 8];
        }
        __syncthreads();
        bf16x8 a0 = *(const bf16x8*)&qt[lm][quad * 8];
        bf16x8 a1 = *(const bf16x8*)&qt[lm][32 + quad * 8];
        bf16x8 b0 = *(const bf16x8*)&kvt[w * 16 + lm][quad * 8];
        bf16x8 b1 = *(const bf16x8*)&kvt[w * 16 + lm][32 + quad * 8];
        f32x4 c = (f32x4){0.f, 0.f, 0.f, 0.f};
        c = __builtin_amdgcn_mfma_f32_16x16x32_bf16(a0, b0, c, 0, 0, 0);
        c = __builtin_amdgcn_mfma_f32_16x16x32_bf16(a1, b1, c, 0, 0, 0);
        const int j = j0 + w * 16 + lm;
        #pragma unroll
        for (int r = 0; r < 4; ++r) {
            const int il = quad * 4 + r;
            Sst[il][j] = c[r] * scale + biasb[il + 511 - j];
        }
        __syncthreads();
    }

    // ---- softmax (full row in LDS, fp32): wave w owns rows 4w..4w+3 ----
    #pragma unroll
    for (int rr = 0; rr < 4; ++rr) {
        const int row = w * 4 + rr;
        float vals[8];
        float mx = -1e30f;
        #pragma unroll
        for (int p = 0; p < 8; ++p) { vals[p] = Sst[row][lane + p * 64]; mx = fmaxf(mx, vals[p]); }
        #pragma unroll
        for (int off = 32; off > 0; off >>= 1) mx = fmaxf(mx, __shfl_xor(mx, off, 64));
        float sum = 0.f;
        #pragma unroll
        for (int p = 0; p < 8; ++p) {
            float e = __expf(vals[p] - mx);
            Sst[row][lane + p * 64] = e;
            sum += e;
        }
        #pragma unroll
        for (int off = 32; off > 0; off >>= 1) sum += __shfl_xor(sum, off, 64);
        if (lane == 0) linv[row] = 1.0f / sum;
    }

    // ---- PV phase: O[i][d] = sum_j P[i][j] V[j][d]; wave w owns d in [16w,16w+16) ----
    f32x4 o = (f32x4){0.f, 0.f, 0.f, 0.f};
    for (int jt = 0; jt < 8; ++jt) {
        const int j0 = jt * 64;
        __syncthreads();   // prior kvt consumers done (also fences softmax->PV)
        #pragma unroll
        for (int i = 0; i < 2; ++i) {
            int chunk = i * 256 + t;
            int row = chunk >> 3, c16 = chunk & 7;
            *(uint4*)&kvt[row][c16 * 8] = *(const uint4*)&vbase[(j0 + row) * DK + c16 * 8];
        }
        __syncthreads();
        #pragma unroll
        for (int ks = 0; ks < 64; ks += 32) {
            ushort8 au;
            #pragma unroll
            for (int jj = 0; jj < 8; ++jj)
                au[jj] = f2bf(Sst[lm][j0 + ks + quad * 8 + jj]);
            ushort8 bu;
            #pragma unroll
            for (int jj = 0; jj < 8; ++jj)
                bu[jj] = kvt[ks + quad * 8 + jj][w * 16 + lm];
            o = __builtin_amdgcn_mfma_f32_16x16x32_bf16(
                __builtin_bit_cast(bf16x8, au), __builtin_bit_cast(bf16x8, bu), o, 0, 0, 0);
        }
    }
    #pragma unroll
    for (int r = 0; r < 4; ++r) {
        const int il = quad * 4 + r;
        const float val = o[r] * linv[il];
        attn_out[(size_t)(b * SEQ + q0 + il) * D_MODEL + h * DK + w * 16 + lm] = f2bf(val);
    }
}

extern "C" void kernel_launch(void* const* d_in, const int* in_sizes, int n_in,
                              void* d_out, int out_size, void* d_ws, size_t ws_size,
                              hipStream_t stream) {
    const float* x   = (const float*)d_in[0];
    const float* Wq  = (const float*)d_in[2];
    const float* bq  = (const float*)d_in[3];
    const float* Wk  = (const float*)d_in[4];
    const float* bk  = (const float*)d_in[5];
    const float* Wv  = (const float*)d_in[6];
    const float* bv  = (const float*)d_in[7];
    const float* Wo  = (const float*)d_in[8];
    const float* bo  = (const float*)d_in[9];
    const float* rel = (const float*)d_in[10];
    float* out = (float*)d_out;

    u16* ws = (u16*)d_ws;
    const size_t WSZ = (size_t)D_MODEL * D_MODEL;   // 1M u16 (2 MB) — reused for all 4 weights
    const size_t TSZ = (size_t)M_TOT * D_MODEL;     // 8M u16 (16 MB)
    u16* Wt  = ws;
    u16* xbf = Wt + WSZ;
    u16* qws = xbf + TSZ;
    u16* kws = qws + TSZ;
    u16* vws = kws + TSZ;
    u16* aws = xbf;   // xbf dead after the 3 qkv GEMMs; reuse for attention output

    dim3 tb(256);
    convert_f32_bf16<<<dim3(M_TOT * D_MODEL / 1024), tb, 0, stream>>>(x, xbf);
    transpose_w<<<dim3(16, 16), tb, 0, stream>>>(Wq, Wt);
    gemm_bt<<<dim3(8, 64), tb, 0, stream>>>(xbf, Wt, bq, qws, 0);
    transpose_w<<<dim3(16, 16), tb, 0, stream>>>(Wk, Wt);
    gemm_bt<<<dim3(8, 64), tb, 0, stream>>>(xbf, Wt, bk, kws, 0);
    transpose_w<<<dim3(16, 16), tb, 0, stream>>>(Wv, Wt);
    gemm_bt<<<dim3(8, 64), tb, 0, stream>>>(xbf, Wt, bv, vws, 0);
    attn_kernel<<<dim3(SEQ / 16, NH, BATCH), tb, 0, stream>>>(qws, kws, vws, rel, aws);
    transpose_w<<<dim3(16, 16), tb, 0, stream>>>(Wo, Wt);
    gemm_bt<<<dim3(8, 64), tb, 0, stream>>>(aws, Wt, bo, (void*)out, 1);
}

// Round 4
// 318.573 us; speedup vs baseline: 1.9659x; 1.9659x over previous
//
#include <hip/hip_runtime.h>
#include <hip/hip_bf16.h>
#include <stdint.h>

#define D_MODEL 1024
#define NH 16
#define SEQ 512
#define DK 64
#define BATCH 16
#define M_TOT (BATCH*SEQ)   // 8192

typedef unsigned short u16;
typedef unsigned int u32;
typedef __attribute__((ext_vector_type(8))) __bf16 bf16x8;
typedef __attribute__((ext_vector_type(4))) u16 ushort4v;
typedef __attribute__((ext_vector_type(4))) float f32x4;

static __device__ __forceinline__ u16 f2bf(float f) {
    union { float f; u32 i; } c; c.f = f;
    u32 u = c.i;
    return (u16)((u + 0x7FFFu + ((u >> 16) & 1u)) >> 16);
}
static __device__ __forceinline__ void async_copy16(const void* g, void* l) {
    __builtin_amdgcn_global_load_lds(
        (const __attribute__((address_space(1))) u32*)g,
        (__attribute__((address_space(3))) u32*)l, 16, 0, 0);
}

// ---------------- f32 -> bf16 convert (x) ----------------
__global__ __launch_bounds__(256) void convert_f32_bf16(const float* __restrict__ in,
                                                        u16* __restrict__ out) {
    const int i = (blockIdx.x * 256 + threadIdx.x) * 4;
    float4 v = *(const float4*)&in[i];
    ushort4v o;
    o[0] = f2bf(v.x); o[1] = f2bf(v.y); o[2] = f2bf(v.z); o[3] = f2bf(v.w);
    *(ushort4v*)&out[i] = o;
}

// ------- weight transpose + convert: Wt[z*1024 + n][k] = bf16(W_z[k][n]) -------
__global__ __launch_bounds__(256) void transpose_w3(const float* __restrict__ W0,
                                                    const float* __restrict__ W1,
                                                    const float* __restrict__ W2,
                                                    u16* __restrict__ Wt) {
    __shared__ u16 tile[64][65];
    const int z = blockIdx.z;
    const float* W = (z == 0) ? W0 : (z == 1) ? W1 : W2;
    const int n0 = blockIdx.x * 64, k0 = blockIdx.y * 64;
    const int t = threadIdx.x;
    #pragma unroll
    for (int p = 0; p < 16; ++p) {
        int idx = p * 256 + t;
        int r = idx >> 6, c = idx & 63;
        tile[r][c] = f2bf(W[(size_t)(k0 + r) * D_MODEL + (n0 + c)]);
    }
    __syncthreads();
    #pragma unroll
    for (int p = 0; p < 16; ++p) {
        int idx = p * 256 + t;
        int r = idx >> 6, c = idx & 63;
        Wt[((size_t)z * D_MODEL + n0 + r) * D_MODEL + (k0 + c)] = tile[c][r];
    }
}

// ------------- C[m,n] = A[m,:]·Bt[n,:] + bias[n]  (m97-style async BT GEMM) -------------
// qkv=1: N=3072 fused; n<1024 -> q [b,h,s,d]; n<2048 -> k [b,h,s,d]; else v^T [b,h,d,s]
// qkv=0: plain f32 [M, D_MODEL] with bias b0
__global__ __launch_bounds__(256) void gemm_bt(const u16* __restrict__ A,
                                               const u16* __restrict__ Bt,
                                               const float* __restrict__ b0,
                                               const float* __restrict__ b1,
                                               const float* __restrict__ b2,
                                               void* __restrict__ o0,
                                               void* __restrict__ o1,
                                               void* __restrict__ o2,
                                               int qkv) {
    __shared__ __attribute__((aligned(16))) u16 Asm[128 * 64];
    __shared__ __attribute__((aligned(16))) u16 Bsm[128 * 64];
    const int t = threadIdx.x;
    const int m0 = blockIdx.y * 128, n0 = blockIdx.x * 128;
    const int lane = t & 63, w = t >> 6;
    const int lm = lane & 15, quad = lane >> 4;
    const int wm = w >> 1, wn = w & 1;

    f32x4 acc[4][4];
    #pragma unroll
    for (int i = 0; i < 4; ++i)
        #pragma unroll
        for (int j = 0; j < 4; ++j) acc[i][j] = (f32x4){0.f, 0.f, 0.f, 0.f};

    for (int kt = 0; kt < D_MODEL / 64; ++kt) {
        const int k0 = kt * 64;
        __syncthreads();   // prior-iteration LDS readers done before overwrite
        #pragma unroll
        for (int i = 0; i < 4; ++i) {
            int chunk = i * 256 + t;
            int row = chunk >> 3, c16 = chunk & 7;
            async_copy16(A + (size_t)(m0 + row) * D_MODEL + k0 + c16 * 8, &Asm[chunk * 8]);
        }
        #pragma unroll
        for (int i = 0; i < 4; ++i) {
            int chunk = i * 256 + t;
            int row = chunk >> 3, c16 = chunk & 7;
            async_copy16(Bt + (size_t)(n0 + row) * D_MODEL + k0 + c16 * 8, &Bsm[chunk * 8]);
        }
        __syncthreads();   // compiler drains vmcnt before s_barrier
        #pragma unroll
        for (int ks = 0; ks < 64; ks += 32) {
            bf16x8 af[4], bfv[4];
            #pragma unroll
            for (int im = 0; im < 4; ++im)
                af[im] = *(const bf16x8*)&Asm[(wm * 64 + im * 16 + lm) * 64 + ks + quad * 8];
            #pragma unroll
            for (int in = 0; in < 4; ++in)
                bfv[in] = *(const bf16x8*)&Bsm[(wn * 64 + in * 16 + lm) * 64 + ks + quad * 8];
            #pragma unroll
            for (int im = 0; im < 4; ++im)
                #pragma unroll
                for (int in = 0; in < 4; ++in)
                    acc[im][in] = __builtin_amdgcn_mfma_f32_16x16x32_bf16(
                        af[im], bfv[in], acc[im][in], 0, 0, 0);
        }
    }
    #pragma unroll
    for (int in = 0; in < 4; ++in) {
        const int n = n0 + wn * 64 + in * 16 + lm;
        const int sel = n >> 10, nn = n & 1023;
        const float bv = qkv ? ((sel == 0) ? b0[nn] : (sel == 1) ? b1[nn] : b2[nn])
                             : b0[n];
        #pragma unroll
        for (int im = 0; im < 4; ++im) {
            #pragma unroll
            for (int r = 0; r < 4; ++r) {
                const int m = m0 + wm * 64 + im * 16 + quad * 4 + r;
                const float val = acc[im][in][r] + bv;
                if (qkv) {
                    const int b = m >> 9, s = m & 511, h = nn >> 6, d = nn & 63;
                    if (sel == 0)
                        ((u16*)o0)[((size_t)(b * NH + h) * SEQ + s) * DK + d] = f2bf(val);
                    else if (sel == 1)
                        ((u16*)o1)[((size_t)(b * NH + h) * SEQ + s) * DK + d] = f2bf(val);
                    else
                        ((u16*)o2)[((size_t)(b * NH + h) * DK + d) * SEQ + s] = f2bf(val);
                } else {
                    ((float*)o0)[(size_t)m * D_MODEL + n] = val;
                }
            }
        }
    }
}

// -------- flash attention: block = (b, h, 64-row q tile); 4 waves x 16 rows --------
__global__ __launch_bounds__(256) void attn_flash(const u16* __restrict__ qg,
                                                  const u16* __restrict__ kg,
                                                  const u16* __restrict__ vTg,
                                                  const float* __restrict__ rel,
                                                  u16* __restrict__ aout) {
    __shared__ __attribute__((aligned(16))) u16 qt[64][72];
    __shared__ __attribute__((aligned(16))) u16 kt[64][72];
    __shared__ __attribute__((aligned(16))) u16 vt[64][72];   // V^T tile: [d][j_local]
    __shared__ __attribute__((aligned(16))) u16 Pl[4][16][72]; // wave-private P
    __shared__ float biasb[576];

    const int t = threadIdx.x;
    const int lane = t & 63, w = t >> 6;
    const int lm = lane & 15, quad = lane >> 4;
    const int q0 = blockIdx.x * 64;
    const int h = blockIdx.y, b = blockIdx.z;
    const size_t bh = (size_t)(b * NH + h);
    const u16* qb = qg + bh * SEQ * DK;
    const u16* kb = kg + bh * SEQ * DK;
    const u16* vb = vTg + bh * DK * SEQ;

    #pragma unroll
    for (int i = 0; i < 2; ++i) {
        int chunk = i * 256 + t, row = chunk >> 3, col = chunk & 7;
        *(uint4*)&qt[row][col * 8] = *(const uint4*)&qb[(q0 + row) * DK + col * 8];
    }
    for (int u = t; u < 575; u += 256) biasb[u] = rel[(q0 + u) * NH + h];

    float mi[4], li[4];
    f32x4 o[4];
    #pragma unroll
    for (int r = 0; r < 4; ++r) { mi[r] = -1e30f; li[r] = 0.f; }
    #pragma unroll
    for (int sd = 0; sd < 4; ++sd) o[sd] = (f32x4){0.f, 0.f, 0.f, 0.f};

    const float scale = 0.125f;  // 1/sqrt(64)

    for (int jt = 0; jt < 8; ++jt) {
        const int j0 = jt * 64;
        __syncthreads();    // prior K/V consumers done
        #pragma unroll
        for (int i = 0; i < 2; ++i) {
            int chunk = i * 256 + t, row = chunk >> 3, col = chunk & 7;
            *(uint4*)&kt[row][col * 8] = *(const uint4*)&kb[(j0 + row) * DK + col * 8];
            *(uint4*)&vt[row][col * 8] = *(const uint4*)&vb[row * SEQ + j0 + col * 8];
        }
        __syncthreads();

        // ---- QK^T: S tile 16(m) x 64(j) per wave, C-layout row=quad*4+r, col=lm ----
        bf16x8 aq0 = *(const bf16x8*)&qt[w * 16 + lm][quad * 8];
        bf16x8 aq1 = *(const bf16x8*)&qt[w * 16 + lm][32 + quad * 8];
        f32x4 s[4];
        #pragma unroll
        for (int js = 0; js < 4; ++js) {
            bf16x8 bk0 = *(const bf16x8*)&kt[js * 16 + lm][quad * 8];
            bf16x8 bk1 = *(const bf16x8*)&kt[js * 16 + lm][32 + quad * 8];
            f32x4 c = (f32x4){0.f, 0.f, 0.f, 0.f};
            c = __builtin_amdgcn_mfma_f32_16x16x32_bf16(aq0, bk0, c, 0, 0, 0);
            c = __builtin_amdgcn_mfma_f32_16x16x32_bf16(aq1, bk1, c, 0, 0, 0);
            s[js] = c;
        }

        // ---- bias + online softmax (row stats live in the owning quad's lanes) ----
        float p[4][4];   // [js][r]
        #pragma unroll
        for (int r = 0; r < 4; ++r) {
            const int rl = w * 16 + quad * 4 + r;
            float mx = -1e30f;
            #pragma unroll
            for (int js = 0; js < 4; ++js) {
                const int jg = j0 + js * 16 + lm;
                float sv = s[js][r] * scale + biasb[rl + 511 - jg];
                p[js][r] = sv;
                mx = fmaxf(mx, sv);
            }
            mx = fmaxf(mx, __shfl_xor(mx, 1, 64));
            mx = fmaxf(mx, __shfl_xor(mx, 2, 64));
            mx = fmaxf(mx, __shfl_xor(mx, 4, 64));
            mx = fmaxf(mx, __shfl_xor(mx, 8, 64));
            const float mnew = fmaxf(mi[r], mx);
            const float alpha = __expf(mi[r] - mnew);
            mi[r] = mnew;
            float rs = 0.f;
            #pragma unroll
            for (int js = 0; js < 4; ++js) {
                float e = __expf(p[js][r] - mnew);
                p[js][r] = e;
                rs += e;
            }
            rs += __shfl_xor(rs, 1, 64);
            rs += __shfl_xor(rs, 2, 64);
            rs += __shfl_xor(rs, 4, 64);
            rs += __shfl_xor(rs, 8, 64);
            li[r] = li[r] * alpha + rs;
            #pragma unroll
            for (int sd = 0; sd < 4; ++sd) o[sd][r] *= alpha;
            #pragma unroll
            for (int js = 0; js < 4; ++js)
                Pl[w][quad * 4 + r][js * 16 + lm] = f2bf(p[js][r]);
        }

        // ---- PV: O[16m x 64d] += P[16m x 64j] V[64j x 64d]; wave-private, no barrier ----
        bf16x8 ap0 = *(const bf16x8*)&Pl[w][lm][quad * 8];
        bf16x8 ap1 = *(const bf16x8*)&Pl[w][lm][32 + quad * 8];
        #pragma unroll
        for (int sd = 0; sd < 4; ++sd) {
            bf16x8 bv0 = *(const bf16x8*)&vt[sd * 16 + lm][quad * 8];
            bf16x8 bv1 = *(const bf16x8*)&vt[sd * 16 + lm][32 + quad * 8];
            o[sd] = __builtin_amdgcn_mfma_f32_16x16x32_bf16(ap0, bv0, o[sd], 0, 0, 0);
            o[sd] = __builtin_amdgcn_mfma_f32_16x16x32_bf16(ap1, bv1, o[sd], 0, 0, 0);
        }
    }

    #pragma unroll
    for (int r = 0; r < 4; ++r) {
        const float rinv = 1.0f / li[r];
        const int srow = q0 + w * 16 + quad * 4 + r;
        #pragma unroll
        for (int sd = 0; sd < 4; ++sd)
            aout[(size_t)(b * SEQ + srow) * D_MODEL + h * DK + sd * 16 + lm] =
                f2bf(o[sd][r] * rinv);
    }
}

extern "C" void kernel_launch(void* const* d_in, const int* in_sizes, int n_in,
                              void* d_out, int out_size, void* d_ws, size_t ws_size,
                              hipStream_t stream) {
    const float* x   = (const float*)d_in[0];
    const float* Wq  = (const float*)d_in[2];
    const float* bq  = (const float*)d_in[3];
    const float* Wk  = (const float*)d_in[4];
    const float* bk  = (const float*)d_in[5];
    const float* Wv  = (const float*)d_in[6];
    const float* bv  = (const float*)d_in[7];
    const float* Wo  = (const float*)d_in[8];
    const float* bo  = (const float*)d_in[9];
    const float* rel = (const float*)d_in[10];
    float* out = (float*)d_out;

    u16* ws = (u16*)d_ws;
    const size_t WSZ = (size_t)D_MODEL * D_MODEL;   // 1M u16 (2 MB)
    const size_t TSZ = (size_t)M_TOT * D_MODEL;     // 8M u16 (16 MB)
    u16* Wt3 = ws;            // 3 MB u16 region (qkv concat); reused for Wo^T
    u16* xbf = Wt3 + 3 * WSZ;
    u16* qws = xbf + TSZ;
    u16* kws = qws + TSZ;
    u16* vws = kws + TSZ;     // stored transposed [b,h,d,s]
    u16* aws = xbf;           // xbf dead after qkv GEMM; reuse — total 70 MB

    dim3 tb(256);
    convert_f32_bf16<<<dim3(M_TOT * D_MODEL / 1024), tb, 0, stream>>>(x, xbf);
    transpose_w3<<<dim3(16, 16, 3), tb, 0, stream>>>(Wq, Wk, Wv, Wt3);
    gemm_bt<<<dim3(24, 64), tb, 0, stream>>>(xbf, Wt3, bq, bk, bv, qws, kws, vws, 1);
    attn_flash<<<dim3(SEQ / 64, NH, BATCH), tb, 0, stream>>>(qws, kws, vws, rel, aws);
    transpose_w3<<<dim3(16, 16, 1), tb, 0, stream>>>(Wo, Wo, Wo, Wt3);
    gemm_bt<<<dim3(8, 64), tb, 0, stream>>>(aws, Wt3, bo, nullptr, nullptr,
                                            (void*)out, nullptr, nullptr, 0);
}

// Round 5
// 285.484 us; speedup vs baseline: 2.1938x; 1.1159x over previous
//
#include <hip/hip_runtime.h>
#include <hip/hip_bf16.h>
#include <stdint.h>

#define D_MODEL 1024
#define NH 16
#define SEQ 512
#define DK 64
#define BATCH 16
#define M_TOT (BATCH*SEQ)   // 8192

typedef unsigned short u16;
typedef unsigned int u32;
typedef __attribute__((ext_vector_type(8))) __bf16 bf16x8;
typedef __attribute__((ext_vector_type(4))) u16 ushort4v;
typedef __attribute__((ext_vector_type(4))) float f32x4;

static __device__ __forceinline__ u16 f2bf(float f) {
    union { float f; u32 i; } c; c.f = f;
    u32 u = c.i;
    return (u16)((u + 0x7FFFu + ((u >> 16) & 1u)) >> 16);
}
static __device__ __forceinline__ void async_copy16(const void* g, void* l) {
    __builtin_amdgcn_global_load_lds(
        (const __attribute__((address_space(1))) u32*)g,
        (__attribute__((address_space(3))) u32*)l, 16, 0, 0);
}

// ---------------- f32 -> bf16 convert (x) ----------------
__global__ __launch_bounds__(256) void convert_f32_bf16(const float* __restrict__ in,
                                                        u16* __restrict__ out) {
    const int i = (blockIdx.x * 256 + threadIdx.x) * 4;
    float4 v = *(const float4*)&in[i];
    ushort4v o;
    o[0] = f2bf(v.x); o[1] = f2bf(v.y); o[2] = f2bf(v.z); o[3] = f2bf(v.w);
    *(ushort4v*)&out[i] = o;
}

// ------- weight transpose + convert: Wt[z*1024 + n][k] = bf16(W_z[k][n]) -------
__global__ __launch_bounds__(256) void transpose_w3(const float* __restrict__ W0,
                                                    const float* __restrict__ W1,
                                                    const float* __restrict__ W2,
                                                    u16* __restrict__ Wt) {
    __shared__ u16 tile[64][65];
    const int z = blockIdx.z;
    const float* W = (z == 0) ? W0 : (z == 1) ? W1 : W2;
    const int n0 = blockIdx.x * 64, k0 = blockIdx.y * 64;
    const int t = threadIdx.x;
    #pragma unroll
    for (int p = 0; p < 16; ++p) {
        int idx = p * 256 + t;
        int r = idx >> 6, c = idx & 63;
        tile[r][c] = f2bf(W[(size_t)(k0 + r) * D_MODEL + (n0 + c)]);
    }
    __syncthreads();
    #pragma unroll
    for (int p = 0; p < 16; ++p) {
        int idx = p * 256 + t;
        int r = idx >> 6, c = idx & 63;
        Wt[((size_t)z * D_MODEL + n0 + r) * D_MODEL + (k0 + c)] = tile[c][r];
    }
}

// ------------- C[m,n] = A[m,:]·Bt[n,:] + bias[n]  (async BT GEMM, XOR-swizzled LDS) -------------
// LDS tile rows are 8 chunks of 16B; chunk c of row holds global chunk c^(row&7).
// Fragment read at chunk (ks/8+quad)^(row&7) -> per-quad 2-way bank aliasing (free).
// qkv=1: N=3072 fused; n<1024 -> q [b,h,s,d]; n<2048 -> k [b,h,s,d]; else v^T [b,h,d,s]
// qkv=0: plain f32 [M, D_MODEL] with bias b0
__global__ __launch_bounds__(256) void gemm_bt(const u16* __restrict__ A,
                                               const u16* __restrict__ Bt,
                                               const float* __restrict__ b0,
                                               const float* __restrict__ b1,
                                               const float* __restrict__ b2,
                                               void* __restrict__ o0,
                                               void* __restrict__ o1,
                                               void* __restrict__ o2,
                                               int qkv) {
    __shared__ __attribute__((aligned(16))) u16 Asm[128 * 64];
    __shared__ __attribute__((aligned(16))) u16 Bsm[128 * 64];
    const int t = threadIdx.x;
    const int m0 = blockIdx.y * 128, n0 = blockIdx.x * 128;
    const int lane = t & 63, w = t >> 6;
    const int lm = lane & 15, quad = lane >> 4;
    const int wm = w >> 1, wn = w & 1;

    f32x4 acc[4][4];
    #pragma unroll
    for (int i = 0; i < 4; ++i)
        #pragma unroll
        for (int j = 0; j < 4; ++j) acc[i][j] = (f32x4){0.f, 0.f, 0.f, 0.f};

    for (int kt = 0; kt < D_MODEL / 64; ++kt) {
        const int k0 = kt * 64;
        __syncthreads();   // prior-iteration LDS readers done before overwrite
        #pragma unroll
        for (int i = 0; i < 4; ++i) {
            int chunk = i * 256 + t;
            int row = chunk >> 3, c = chunk & 7;
            int cs = c ^ (row & 7);   // swizzled source chunk
            async_copy16(A + (size_t)(m0 + row) * D_MODEL + k0 + cs * 8, &Asm[chunk * 8]);
        }
        #pragma unroll
        for (int i = 0; i < 4; ++i) {
            int chunk = i * 256 + t;
            int row = chunk >> 3, c = chunk & 7;
            int cs = c ^ (row & 7);
            async_copy16(Bt + (size_t)(n0 + row) * D_MODEL + k0 + cs * 8, &Bsm[chunk * 8]);
        }
        __syncthreads();   // drains vmcnt before s_barrier
        #pragma unroll
        for (int ks = 0; ks < 64; ks += 32) {
            const int cbase = ks >> 3;   // 0 or 4
            bf16x8 af[4], bfv[4];
            #pragma unroll
            for (int im = 0; im < 4; ++im) {
                const int row = wm * 64 + im * 16 + lm;
                const int c = (cbase + quad) ^ (row & 7);
                af[im] = *(const bf16x8*)&Asm[row * 64 + c * 8];
            }
            #pragma unroll
            for (int in = 0; in < 4; ++in) {
                const int row = wn * 64 + in * 16 + lm;
                const int c = (cbase + quad) ^ (row & 7);
                bfv[in] = *(const bf16x8*)&Bsm[row * 64 + c * 8];
            }
            #pragma unroll
            for (int im = 0; im < 4; ++im)
                #pragma unroll
                for (int in = 0; in < 4; ++in)
                    acc[im][in] = __builtin_amdgcn_mfma_f32_16x16x32_bf16(
                        af[im], bfv[in], acc[im][in], 0, 0, 0);
        }
    }
    #pragma unroll
    for (int in = 0; in < 4; ++in) {
        const int n = n0 + wn * 64 + in * 16 + lm;
        const int sel = n >> 10, nn = n & 1023;   // sel uniform per block (n0 mult of 128)
        const float bv = qkv ? ((sel == 0) ? b0[nn] : (sel == 1) ? b1[nn] : b2[nn])
                             : b0[n];
        #pragma unroll
        for (int im = 0; im < 4; ++im) {
            const int mb = m0 + wm * 64 + im * 16 + quad * 4;
            if (qkv) {
                const int b = mb >> 9, h = nn >> 6, d = nn & 63;
                if (sel == 2) {
                    // v^T [b,h,d,s]: 4 r-values are consecutive s -> one 8B store
                    const int s = mb & 511;
                    ushort4v pk;
                    #pragma unroll
                    for (int r = 0; r < 4; ++r) pk[r] = f2bf(acc[im][in][r] + bv);
                    *(ushort4v*)&((u16*)o2)[((size_t)(b * NH + h) * DK + d) * SEQ + s] = pk;
                } else {
                    u16* dst = (sel == 0) ? (u16*)o0 : (u16*)o1;
                    #pragma unroll
                    for (int r = 0; r < 4; ++r) {
                        const int s = (mb + r) & 511;
                        dst[((size_t)(b * NH + h) * SEQ + s) * DK + d] =
                            f2bf(acc[im][in][r] + bv);
                    }
                }
            } else {
                #pragma unroll
                for (int r = 0; r < 4; ++r)
                    ((float*)o0)[(size_t)(mb + r) * D_MODEL + n] = acc[im][in][r] + bv;
            }
        }
    }
}

// -------- flash attention: block = (b, h, 64-row q tile); 4 waves x 16 rows --------
__global__ __launch_bounds__(256) void attn_flash(const u16* __restrict__ qg,
                                                  const u16* __restrict__ kg,
                                                  const u16* __restrict__ vTg,
                                                  const float* __restrict__ rel,
                                                  u16* __restrict__ aout) {
    __shared__ __attribute__((aligned(16))) u16 qt[64][72];
    __shared__ __attribute__((aligned(16))) u16 kt[64][72];
    __shared__ __attribute__((aligned(16))) u16 vt[64][72];   // V^T tile: [d][j_local]
    __shared__ __attribute__((aligned(16))) u16 Pl[4][16][72]; // wave-private P
    __shared__ float biasb[576];

    const int t = threadIdx.x;
    const int lane = t & 63, w = t >> 6;
    const int lm = lane & 15, quad = lane >> 4;
    const int q0 = blockIdx.x * 64;
    const int h = blockIdx.y, b = blockIdx.z;
    const size_t bh = (size_t)(b * NH + h);
    const u16* qb = qg + bh * SEQ * DK;
    const u16* kb = kg + bh * SEQ * DK;
    const u16* vb = vTg + bh * DK * SEQ;

    #pragma unroll
    for (int i = 0; i < 2; ++i) {
        int chunk = i * 256 + t, row = chunk >> 3, col = chunk & 7;
        *(uint4*)&qt[row][col * 8] = *(const uint4*)&qb[(q0 + row) * DK + col * 8];
    }
    for (int u = t; u < 575; u += 256) biasb[u] = rel[(q0 + u) * NH + h];

    float mi[4], li[4];
    f32x4 o[4];
    #pragma unroll
    for (int r = 0; r < 4; ++r) { mi[r] = -1e30f; li[r] = 0.f; }
    #pragma unroll
    for (int sd = 0; sd < 4; ++sd) o[sd] = (f32x4){0.f, 0.f, 0.f, 0.f};

    const float scale = 0.125f;  // 1/sqrt(64)

    for (int jt = 0; jt < 8; ++jt) {
        const int j0 = jt * 64;
        __syncthreads();    // prior K/V consumers done
        #pragma unroll
        for (int i = 0; i < 2; ++i) {
            int chunk = i * 256 + t, row = chunk >> 3, col = chunk & 7;
            *(uint4*)&kt[row][col * 8] = *(const uint4*)&kb[(j0 + row) * DK + col * 8];
            *(uint4*)&vt[row][col * 8] = *(const uint4*)&vb[row * SEQ + j0 + col * 8];
        }
        __syncthreads();

        // ---- QK^T: S tile 16(m) x 64(j) per wave, C-layout row=quad*4+r, col=lm ----
        bf16x8 aq0 = *(const bf16x8*)&qt[w * 16 + lm][quad * 8];
        bf16x8 aq1 = *(const bf16x8*)&qt[w * 16 + lm][32 + quad * 8];
        f32x4 s[4];
        #pragma unroll
        for (int js = 0; js < 4; ++js) {
            bf16x8 bk0 = *(const bf16x8*)&kt[js * 16 + lm][quad * 8];
            bf16x8 bk1 = *(const bf16x8*)&kt[js * 16 + lm][32 + quad * 8];
            f32x4 c = (f32x4){0.f, 0.f, 0.f, 0.f};
            c = __builtin_amdgcn_mfma_f32_16x16x32_bf16(aq0, bk0, c, 0, 0, 0);
            c = __builtin_amdgcn_mfma_f32_16x16x32_bf16(aq1, bk1, c, 0, 0, 0);
            s[js] = c;
        }

        // ---- bias + online softmax (row stats live in the owning quad's lanes) ----
        float p[4][4];   // [js][r]
        #pragma unroll
        for (int r = 0; r < 4; ++r) {
            const int rl = w * 16 + quad * 4 + r;
            float mx = -1e30f;
            #pragma unroll
            for (int js = 0; js < 4; ++js) {
                const int jg = j0 + js * 16 + lm;
                float sv = s[js][r] * scale + biasb[rl + 511 - jg];
                p[js][r] = sv;
                mx = fmaxf(mx, sv);
            }
            mx = fmaxf(mx, __shfl_xor(mx, 1, 64));
            mx = fmaxf(mx, __shfl_xor(mx, 2, 64));
            mx = fmaxf(mx, __shfl_xor(mx, 4, 64));
            mx = fmaxf(mx, __shfl_xor(mx, 8, 64));
            const float mnew = fmaxf(mi[r], mx);
            const float alpha = __expf(mi[r] - mnew);
            mi[r] = mnew;
            float rs = 0.f;
            #pragma unroll
            for (int js = 0; js < 4; ++js) {
                float e = __expf(p[js][r] - mnew);
                p[js][r] = e;
                rs += e;
            }
            rs += __shfl_xor(rs, 1, 64);
            rs += __shfl_xor(rs, 2, 64);
            rs += __shfl_xor(rs, 4, 64);
            rs += __shfl_xor(rs, 8, 64);
            li[r] = li[r] * alpha + rs;
            #pragma unroll
            for (int sd = 0; sd < 4; ++sd) o[sd][r] *= alpha;
            #pragma unroll
            for (int js = 0; js < 4; ++js)
                Pl[w][quad * 4 + r][js * 16 + lm] = f2bf(p[js][r]);
        }

        // ---- PV: O[16m x 64d] += P[16m x 64j] V[64j x 64d]; wave-private, no barrier ----
        bf16x8 ap0 = *(const bf16x8*)&Pl[w][lm][quad * 8];
        bf16x8 ap1 = *(const bf16x8*)&Pl[w][lm][32 + quad * 8];
        #pragma unroll
        for (int sd = 0; sd < 4; ++sd) {
            bf16x8 bv0 = *(const bf16x8*)&vt[sd * 16 + lm][quad * 8];
            bf16x8 bv1 = *(const bf16x8*)&vt[sd * 16 + lm][32 + quad * 8];
            o[sd] = __builtin_amdgcn_mfma_f32_16x16x32_bf16(ap0, bv0, o[sd], 0, 0, 0);
            o[sd] = __builtin_amdgcn_mfma_f32_16x16x32_bf16(ap1, bv1, o[sd], 0, 0, 0);
        }
    }

    #pragma unroll
    for (int r = 0; r < 4; ++r) {
        const float rinv = 1.0f / li[r];
        const int srow = q0 + w * 16 + quad * 4 + r;
        #pragma unroll
        for (int sd = 0; sd < 4; ++sd)
            aout[(size_t)(b * SEQ + srow) * D_MODEL + h * DK + sd * 16 + lm] =
                f2bf(o[sd][r] * rinv);
    }
}

extern "C" void kernel_launch(void* const* d_in, const int* in_sizes, int n_in,
                              void* d_out, int out_size, void* d_ws, size_t ws_size,
                              hipStream_t stream) {
    const float* x   = (const float*)d_in[0];
    const float* Wq  = (const float*)d_in[2];
    const float* bq  = (const float*)d_in[3];
    const float* Wk  = (const float*)d_in[4];
    const float* bk  = (const float*)d_in[5];
    const float* Wv  = (const float*)d_in[6];
    const float* bv  = (const float*)d_in[7];
    const float* Wo  = (const float*)d_in[8];
    const float* bo  = (const float*)d_in[9];
    const float* rel = (const float*)d_in[10];
    float* out = (float*)d_out;

    u16* ws = (u16*)d_ws;
    const size_t WSZ = (size_t)D_MODEL * D_MODEL;   // 1M u16 (2 MB)
    const size_t TSZ = (size_t)M_TOT * D_MODEL;     // 8M u16 (16 MB)
    u16* Wt3 = ws;            // 6 MB u16 region (qkv concat); reused for Wo^T
    u16* xbf = Wt3 + 3 * WSZ;
    u16* qws = xbf + TSZ;
    u16* kws = qws + TSZ;
    u16* vws = kws + TSZ;     // stored transposed [b,h,d,s]
    u16* aws = xbf;           // xbf dead after qkv GEMM; reuse — total 70 MB

    dim3 tb(256);
    convert_f32_bf16<<<dim3(M_TOT * D_MODEL / 1024), tb, 0, stream>>>(x, xbf);
    transpose_w3<<<dim3(16, 16, 3), tb, 0, stream>>>(Wq, Wk, Wv, Wt3);
    gemm_bt<<<dim3(24, 64), tb, 0, stream>>>(xbf, Wt3, bq, bk, bv, qws, kws, vws, 1);
    attn_flash<<<dim3(SEQ / 64, NH, BATCH), tb, 0, stream>>>(qws, kws, vws, rel, aws);
    transpose_w3<<<dim3(16, 16, 1), tb, 0, stream>>>(Wo, Wo, Wo, Wt3);
    gemm_bt<<<dim3(8, 64), tb, 0, stream>>>(aws, Wt3, bo, nullptr, nullptr,
                                            (void*)out, nullptr, nullptr, 0);
}